// Round 14
// baseline (563.166 us; speedup 1.0000x reference)
//
#include <hip/hip_runtime.h>

#define NN 100000
#define EE 3200000
#define N2 100032   // NN rounded up to 64
#define NBUCK 782   // ceil(NN/128)
#define CPAD 16     // counter padding (one per 64B line)
#define CHUNK 12288 // edges per binB block
#define CAP 5120    // fixed bucket capacity (mean 4096 + 16 sigma)
#define NB_BINB 261 // ceil(EE/CHUNK)

typedef _Float16 f16;
typedef _Float16 f16x8 __attribute__((ext_vector_type(8)));
typedef float f32x4 __attribute__((ext_vector_type(4)));
typedef unsigned int u32;

#define MFMA(a, b, c) __builtin_amdgcn_mfma_f32_16x16x32_f16((a), (b), (c), 0, 0, 0)

// ---------------- weight pack helper (bias folded at k=95/159) ----------------

__device__ __forceinline__ f16 pack_one(const float* __restrict__ W,
                                        const float* __restrict__ bias, int rel, int K, int Nc,
                                        int KG, int trans, int bslot) {
  int e = rel & 7, nn = (rel >> 3) & 15;
  int g = (rel >> 7) % KG, nb = (rel >> 7) / KG;
  int k = g * 8 + e, n = nb * 16 + nn;
  float v = 0.f;
  if (n < Nc) {
    if (k < K) v = trans ? W[n * K + k] : W[k * Nc + n];
    else if (k == bslot) v = bias[n];
  }
  return (f16)v;
}

// ---------------- fused binB (blocks 0..260) + prep (rest) ----------------

__global__ __launch_bounds__(256) void binBprep_kernel(const int* __restrict__ src,
                                                       const int* __restrict__ dst,
                                                       int* __restrict__ bcur,
                                                       u32* __restrict__ ebuf,
                                                       const float* __restrict__ x,
                                                       f16* __restrict__ xp,
                                                       f16* __restrict__ zm,
                                                       const float* __restrict__ w1,
                                                       const float* __restrict__ b1,
                                                       const float* __restrict__ w2,
                                                       const float* __restrict__ b2,
                                                       const float* __restrict__ wih,
                                                       const float* __restrict__ bih,
                                                       const float* __restrict__ whh,
                                                       const float* __restrict__ bhh,
                                                       const float* __restrict__ wc1,
                                                       const float* __restrict__ bc1,
                                                       const float* __restrict__ wc2,
                                                       const float* __restrict__ bc2,
                                                       f16* __restrict__ wp) {
  __shared__ int hist[NBUCK];
  __shared__ int base[NBUCK];
  int b = blockIdx.x, tid = threadIdx.x;
  if (b < NB_BINB) {
    int e0 = b * CHUNK;
    int e1 = e0 + CHUNK;
    if (e1 > EE) e1 = EE;
    for (int i = tid; i < NBUCK; i += 256) hist[i] = 0;
    __syncthreads();
    for (int e = e0 + tid * 4; e < e1; e += 1024) {
      int4 d = *(const int4*)(dst + e);
      atomicAdd(&hist[d.x >> 7], 1);
      atomicAdd(&hist[d.y >> 7], 1);
      atomicAdd(&hist[d.z >> 7], 1);
      atomicAdd(&hist[d.w >> 7], 1);
    }
    __syncthreads();
    for (int i = tid; i < NBUCK; i += 256) {
      int c = hist[i];
      if (c) base[i] = i * CAP + atomicAdd(&bcur[i * CPAD], c);
    }
    __syncthreads();
    for (int i = tid; i < NBUCK; i += 256) hist[i] = 0;
    __syncthreads();
    for (int e = e0 + tid * 4; e < e1; e += 1024) {
      int4 d = *(const int4*)(dst + e);
      int4 s = *(const int4*)(src + e);
      int bb, loc;
      bb = d.x >> 7; loc = atomicAdd(&hist[bb], 1);
      ebuf[base[bb] + loc] = (u32)s.x | ((u32)(d.x & 127) << 17);
      bb = d.y >> 7; loc = atomicAdd(&hist[bb], 1);
      ebuf[base[bb] + loc] = (u32)s.y | ((u32)(d.y & 127) << 17);
      bb = d.z >> 7; loc = atomicAdd(&hist[bb], 1);
      ebuf[base[bb] + loc] = (u32)s.z | ((u32)(d.z & 127) << 17);
      bb = d.w >> 7; loc = atomicAdd(&hist[bb], 1);
      ebuf[base[bb] + loc] = (u32)s.w | ((u32)(d.w & 127) << 17);
    }
  } else if (b < NB_BINB + 470) {
    int i = (b - NB_BINB) * 256 + tid;   // 120320 = 470*256
    if (i >= 120320) return;
    f16 v;
    if (i < 7680) v = pack_one(w1, b1, i, 75, 75, 12, 0, 95);
    else if (i < 15360) v = pack_one(w2, b2, i - 7680, 75, 75, 12, 0, 95);
    else if (i < 38400) {
      int r = i - 15360, g = r / 7680;
      v = pack_one(wih + g * 5625, bih + g * 75, r - g * 7680, 75, 75, 12, 1, 95);
    } else if (i < 61440) {
      int r = i - 38400, g = r / 7680;
      v = pack_one(whh + g * 5625, bhh + g * 75, r - g * 7680, 75, 75, 12, 1, 95);
    } else if (i < 107520) {
      int rel = i - 61440;
      int e = rel & 7, nn = (rel >> 3) & 15;
      int g = (rel >> 7) % 36, nb = (rel >> 7) / 36;
      int q = g * 8 + e, buf = q / 96, kk = q - buf * 96, n = nb * 16 + nn;
      float f = 0.f;
      if (n < 150) {
        if (kk < 75) f = wc1[(buf * 75 + kk) * 150 + n];
        else if (kk == 95 && buf == 0) f = bc1[n];
      }
      v = (f16)f;
    } else v = pack_one(wc2, bc2, i - 107520, 150, 75, 20, 0, 159);
    wp[i] = v;
  } else if (b < NB_BINB + 470 + 6252) {
    int i = (b - NB_BINB - 470) * 256 + tid;   // N2*16 = 1600512 = 6252*256
    int r = i >> 4, c = i & 15;
    zm[r * 96 + 80 + c] = (f16)(c == 15 ? 1.f : 0.f);
  } else {
    int i = (b - NB_BINB - 470 - 6252) * 256 + tid;  // N2*96 = 9603072 = 37512*256
    int r = i / 96, c = i - r * 96;
    float v = (r < NN && c < 75) ? x[r * 75 + c] : (c == 95 ? 1.f : 0.f);
    xp[i] = (f16)v;
  }
}

// ---------------- binC: per-bucket node-grouping into csr + st/ct ----------------

__global__ __launch_bounds__(256) void binC_kernel(const u32* __restrict__ ebuf,
                                                   const int* __restrict__ bcur,
                                                   int* __restrict__ st,
                                                   int* __restrict__ ct,
                                                   int* __restrict__ csr) {
  __shared__ int cnt[128], sc[128], cur[128];
  int b = blockIdx.x, tid = threadIdx.x;
  int e0 = b * CAP;
  int e1 = e0 + bcur[b * CPAD];   // cursor = bucket count
  if (tid < 128) cnt[tid] = 0;
  __syncthreads();
  for (int e = e0 + tid; e < e1; e += 256) atomicAdd(&cnt[ebuf[e] >> 17], 1);
  __syncthreads();
  if (tid < 128) sc[tid] = cnt[tid];
  __syncthreads();
  for (int off = 1; off < 128; off <<= 1) {
    int t = 0;
    if (tid < 128 && tid >= off) t = sc[tid - off];
    __syncthreads();
    if (tid < 128) sc[tid] += t;
    __syncthreads();
  }
  if (tid < 128) {
    int gpos = e0 + sc[tid] - cnt[tid];
    int node = b * 128 + tid;
    if (node < NN) {
      st[node] = gpos;
      ct[node] = cnt[tid];
    }
    cur[tid] = gpos;
  }
  __syncthreads();
  for (int e = e0 + tid; e < e1; e += 256) {
    u32 p = ebuf[e];
    int pos = atomicAdd(&cur[p >> 17], 1);
    csr[pos] = (int)(p & 0x1FFFFu);
  }
}

// ---------------- aggregation: wave/node, 6-way edge split, 96-stride gather ----------------

__global__ __launch_bounds__(256) void aggz_kernel(const f16* __restrict__ xc,
                                                   const int* __restrict__ st,
                                                   const int* __restrict__ ct,
                                                   const int* __restrict__ csr,
                                                   const float* __restrict__ eps,
                                                   f16* __restrict__ zm) {
  int tid = threadIdx.x;
  int l = tid & 63;
  int n = blockIdx.x * 4 + (tid >> 6);
  if (n >= NN) return;
  int s = l / 10, j = l - s * 10;
  int e0 = st[n], e1 = e0 + ct[n];
  float acc[8] = {0, 0, 0, 0, 0, 0, 0, 0};
  if (l < 60) {
#pragma unroll 4
    for (int e = e0 + s; e < e1; e += 6) {
      int sr = csr[e];
      f16x8 v = *(const f16x8*)(xc + sr * 96 + j * 8);
#pragma unroll
      for (int k = 0; k < 8; ++k) acc[k] += (float)v[k];
    }
  }
  int l1 = (l + 30) & 63, l2 = (l + 10) & 63, l3 = (l + 20) & 63;
#pragma unroll
  for (int k = 0; k < 8; ++k) {
    float t = __shfl(acc[k], l1, 64);
    if (l < 30) acc[k] += t;
    t = __shfl(acc[k], l2, 64);
    if (l < 10) acc[k] += t;
    t = __shfl(acc[k], l3, 64);
    if (l < 10) acc[k] += t;
  }
  if (l < 10) {
    f16x8 self = *(const f16x8*)(xc + n * 96 + j * 8);
    float ep = 1.f + eps[0];
    f16x8 o;
#pragma unroll
    for (int k = 0; k < 8; ++k) o[k] = (f16)(ep * (float)self[k] + acc[k]);
    *(f16x8*)(zm + n * 96 + j * 8) = o;   // cols 0..79; pads pre-set by prep
  }
}

// ---------------- shared device body: MLP + GRU -> h' left in Ld (cols 0..95) ----------------

__device__ __forceinline__ void mlpgru_body(const f16* __restrict__ zm,
                                            const f16* __restrict__ hcur,
                                            const f16* __restrict__ w1p,
                                            const f16* __restrict__ w2p,
                                            const f16* __restrict__ wihp,
                                            const f16* __restrict__ whhp,
                                            f16* Ld, f16* Hd,
                                            int row0, int lm, int lg) {
  const f16* ar = zm + (row0 + lm) * 96;
  const f16* hr = hcur + (row0 + lm) * 96;
  f16x8 a0 = *(const f16x8*)(ar + lg * 8);
  f16x8 a1 = *(const f16x8*)(ar + 32 + lg * 8);
  f16x8 a2 = *(const f16x8*)(ar + 64 + lg * 8);
  f16x8 h0 = *(const f16x8*)(hr + lg * 8);
  f16x8 h1 = *(const f16x8*)(hr + 32 + lg * 8);
  f16x8 h2 = *(const f16x8*)(hr + 64 + lg * 8);
  *(f16x8*)(Hd + lm * 104 + lg * 8) = h0;
  *(f16x8*)(Hd + lm * 104 + 32 + lg * 8) = h1;
  *(f16x8*)(Hd + lm * 104 + 64 + lg * 8) = h2;
  // --- MLP layer 1 (bias folded: zm col95=1, w1p k95=b1)
#pragma unroll
  for (int nb = 0; nb < 5; ++nb) {
    const f16* bp = w1p + ((nb * 12 + lg) * 16 + lm) * 8;
    f32x4 acc = (f32x4){0.f, 0.f, 0.f, 0.f};
    acc = MFMA(a0, *(const f16x8*)bp, acc);
    acc = MFMA(a1, *(const f16x8*)(bp + 512), acc);
    acc = MFMA(a2, *(const f16x8*)(bp + 1024), acc);
#pragma unroll
    for (int r = 0; r < 4; ++r)
      Ld[(lg * 4 + r) * 104 + nb * 16 + lm] = (f16)fmaxf(acc[r], 0.f);
  }
#pragma unroll
  for (int c = 0; c < 4; ++c) {
    int col = 80 + lg * 4 + c;
    Ld[lm * 104 + col] = (f16)(col == 95 ? 1.f : 0.f);
  }
  // --- MLP layer 2
  const f16* Lr = Ld + lm * 104;
  f16x8 c0 = *(const f16x8*)(Lr + lg * 8);
  f16x8 c1 = *(const f16x8*)(Lr + 32 + lg * 8);
  f16x8 c2 = *(const f16x8*)(Lr + 64 + lg * 8);
#pragma unroll
  for (int nb = 0; nb < 5; ++nb) {
    const f16* bp = w2p + ((nb * 12 + lg) * 16 + lm) * 8;
    f32x4 acc = (f32x4){0.f, 0.f, 0.f, 0.f};
    acc = MFMA(c0, *(const f16x8*)bp, acc);
    acc = MFMA(c1, *(const f16x8*)(bp + 512), acc);
    acc = MFMA(c2, *(const f16x8*)(bp + 1024), acc);
#pragma unroll
    for (int r = 0; r < 4; ++r)
      Ld[(lg * 4 + r) * 104 + nb * 16 + lm] = (f16)fmaxf(acc[r], 0.f);
  }
  // --- GRU per-nb (register-lean)
  f16x8 am0 = *(const f16x8*)(Lr + lg * 8);
  f16x8 am1 = *(const f16x8*)(Lr + 32 + lg * 8);
  f16x8 am2 = *(const f16x8*)(Lr + 64 + lg * 8);
#pragma unroll 1
  for (int nb = 0; nb < 5; ++nb) {
    f32x4 rg = (f32x4){0.f, 0.f, 0.f, 0.f};
    f32x4 zg = rg, ni = rg, nh = rg;
#pragma unroll
    for (int s = 0; s < 3; ++s) {
      f16x8 ams = (s == 0) ? am0 : (s == 1) ? am1 : am2;
      f16x8 ahs = (s == 0) ? h0 : (s == 1) ? h1 : h2;
      int fo = ((nb * 12 + s * 4 + lg) * 16 + lm) * 8;
      rg = MFMA(ams, *(const f16x8*)(wihp + fo), rg);
      rg = MFMA(ahs, *(const f16x8*)(whhp + fo), rg);
      zg = MFMA(ams, *(const f16x8*)(wihp + 7680 + fo), zg);
      zg = MFMA(ahs, *(const f16x8*)(whhp + 7680 + fo), zg);
      ni = MFMA(ams, *(const f16x8*)(wihp + 15360 + fo), ni);
      nh = MFMA(ahs, *(const f16x8*)(whhp + 15360 + fo), nh);
    }
#pragma unroll
    for (int r = 0; r < 4; ++r) {
      int n = nb * 16 + lm;
      float hval = (float)Hd[(lg * 4 + r) * 104 + n];
      float rv = 1.f / (1.f + __expf(-rg[r]));
      float zv = 1.f / (1.f + __expf(-zg[r]));
      float u = ni[r] + rv * nh[r];
      float t = __expf(-2.f * fabsf(u));
      float nv = copysignf((1.f - t) / (1.f + t), u);
      float hp = zv * (hval - nv) + nv;
      Ld[(lg * 4 + r) * 104 + n] = (f16)hp;
    }
  }
}

// ---------------- mlpgru (iterations 0,1): h' -> hb_out ----------------

__global__ __launch_bounds__(256) void mlpgru_kernel(const f16* __restrict__ zm,
                                                     const f16* __restrict__ hcur,
                                                     const f16* __restrict__ w1p,
                                                     const f16* __restrict__ w2p,
                                                     const f16* __restrict__ wihp,
                                                     const f16* __restrict__ whhp,
                                                     f16* __restrict__ hb_out) {
  __shared__ f16 Ls[4][16 * 104];
  __shared__ f16 Hs[4][16 * 104];
  int tid = threadIdx.x;
  int w = tid >> 6, l = tid & 63, lm = l & 15, lg = l >> 4;
  int row0 = blockIdx.x * 64 + w * 16;
  f16* Ld = Ls[w];
  mlpgru_body(zm, hcur, w1p, w2p, wihp, whhp, Ld, Hs[w], row0, lm, lg);
#pragma unroll
  for (int k = 0; k < 3; ++k) {
    int p = l + 64 * k;
    int r = p / 12, sl = p - r * 12;
    f16x8 v = *(const f16x8*)(Ld + r * 104 + sl * 8);
    *(f16x8*)(hb_out + (row0 + r) * 96 + sl * 8) = v;
  }
}

// ---------------- mlpgru_last (iteration 2): outx + fused readout, hb loads hoisted ----------

__global__ __launch_bounds__(256) void mlpgru_last_kernel(const f16* __restrict__ zm,
                                                          const f16* __restrict__ hcur,
                                                          const f16* __restrict__ w1p,
                                                          const f16* __restrict__ w2p,
                                                          const f16* __restrict__ wihp,
                                                          const f16* __restrict__ whhp,
                                                          const f16* __restrict__ hb0,
                                                          const f16* __restrict__ hb1,
                                                          const f16* __restrict__ wc1p,
                                                          const f16* __restrict__ wc2p,
                                                          float* __restrict__ outx,
                                                          float* __restrict__ outr) {
  __shared__ f16 LsB[4][3392];     // per-wave: [0,1664)=Ld, [1696,3360)=Hd; reused for r1/fp32
  int tid = threadIdx.x;
  int w = tid >> 6, l = tid & 63, lm = l & 15, lg = l >> 4;
  int row0 = blockIdx.x * 64 + w * 16;
  int row = row0 + lm;
  // HOISTED: readout A-fragments from hb0/hb1 — independent of the body; issue
  // them first so their ~900cy latency hides under the MLP+GRU compute.
  f16x8 a[9];
#pragma unroll
  for (int s = 0; s < 3; ++s) {
    a[s]     = *(const f16x8*)(hb0 + row * 96 + s * 32 + lg * 8);
    a[3 + s] = *(const f16x8*)(hb1 + row * 96 + s * 32 + lg * 8);
  }
  f16* Ld = LsB[w];
  f16* Hd = LsB[w] + 1696;
  mlpgru_body(zm, hcur, w1p, w2p, wihp, whhp, Ld, Hd, row0, lm, lg);
  // --- outx (fp32 final node states) from Ld
  for (int k = 0; k < 19; ++k) {
    int p = l + 64 * k;
    int gi = row0 * 75 + p;
    if (p < 1200 && gi < NN * 75) {
      int r = p / 75, c = p - r * 75;
      outx[gi] = (float)Ld[r * 104 + c];
    }
  }
  // --- h2 fragments from Ld (this iteration's h')
#pragma unroll
  for (int s = 0; s < 3; ++s)
    a[6 + s] = *(const f16x8*)(Ld + lm * 104 + s * 32 + lg * 8);
  // r1 = relu(cat @ wc1 + bc1) -> LDS stride 168 (overwrites Ld/Hd; a[] already in regs)
#pragma unroll
  for (int nb = 0; nb < 10; ++nb) {
    f32x4 acc = (f32x4){0.f, 0.f, 0.f, 0.f};
#pragma unroll
    for (int s = 0; s < 9; ++s)
      acc = MFMA(a[s], *(const f16x8*)(wc1p + ((nb * 36 + 4 * s + lg) * 16 + lm) * 8), acc);
#pragma unroll
    for (int r = 0; r < 4; ++r) {
      int n = nb * 16 + lm;
      float v = fmaxf(acc[r], 0.f);
      if (n >= 150) v = (n == 159) ? 1.f : 0.f;   // pad + bias slot (wc2p k159 = bc2)
      LsB[w][(lg * 4 + r) * 168 + n] = (f16)v;
    }
  }
  const f16* Lr2 = LsB[w] + lm * 168;
  f16x8 a2[5];
#pragma unroll
  for (int s = 0; s < 5; ++s) a2[s] = *(const f16x8*)(Lr2 + s * 32 + lg * 8);
  f32x4 acc2[5];
#pragma unroll
  for (int nb = 0; nb < 5; ++nb) {
    acc2[nb] = (f32x4){0.f, 0.f, 0.f, 0.f};
#pragma unroll
    for (int s = 0; s < 5; ++s)
      acc2[nb] = MFMA(a2[s], *(const f16x8*)(wc2p + ((nb * 20 + s * 4 + lg) * 16 + lm) * 8),
                      acc2[nb]);
  }
  float* Lf = (float*)LsB[w];
#pragma unroll
  for (int nb = 0; nb < 5; ++nb)
#pragma unroll
    for (int r = 0; r < 4; ++r) {
      int n = nb * 16 + lm;
      if (n < 75) Lf[(lg * 4 + r) * 76 + n] = acc2[nb][r];
    }
  for (int k = 0; k < 19; ++k) {
    int p = l + 64 * k;
    int gi = row0 * 75 + p;
    if (p < 1200 && gi < NN * 75) {
      int r = p / 75, c = p - r * 75;
      outr[gi] = Lf[r * 76 + c];
    }
  }
}

// ---------------- launch ----------------

extern "C" void kernel_launch(void* const* d_in, const int* in_sizes, int n_in,
                              void* d_out, int out_size, void* d_ws, size_t ws_size,
                              hipStream_t stream) {
  const float* x    = (const float*)d_in[0];
  const int*   ei   = (const int*)d_in[1];
  const float* eps  = (const float*)d_in[2];
  const float* w1   = (const float*)d_in[3];
  const float* b1   = (const float*)d_in[4];
  const float* w2   = (const float*)d_in[5];
  const float* b2   = (const float*)d_in[6];
  const float* w_ih = (const float*)d_in[7];
  const float* w_hh = (const float*)d_in[8];
  const float* b_ih = (const float*)d_in[9];
  const float* b_hh = (const float*)d_in[10];
  const float* wc1  = (const float*)d_in[11];
  const float* bc1  = (const float*)d_in[12];
  const float* wc2  = (const float*)d_in[13];
  const float* bc2  = (const float*)d_in[14];

  const int* srcv = ei;
  const int* dstv = ei + EE;

  float* out_x = (float*)d_out;              // N*75 final node states (fp32)
  float* out_r = out_x + NN * 75;            // N*75 readout (fp32)

  f16* zm   = (f16*)d_ws;                    // N2*96
  f16* x0   = zm + (size_t)N2 * 96;          // N2*96
  f16* hb0  = x0 + (size_t)N2 * 96;          // N2*96
  f16* hb1  = hb0 + (size_t)N2 * 96;         // N2*96
  f16* wp   = hb1 + (size_t)N2 * 96;         // packed weights, 120320 f16
  f16* w1p  = wp;
  f16* w2p  = wp + 7680;
  f16* wihp = wp + 15360;                    // 3 gates x 7680
  f16* whhp = wp + 38400;
  f16* wc1p = wp + 61440;                    // 46080 (KG=36, NB=10)
  f16* wc2p = wp + 107520;                   // 12800
  u32* ebuf = (u32*)(wp + 120320);           // NBUCK*CAP
  int* csr  = (int*)(ebuf + (size_t)NBUCK * CAP);  // NBUCK*CAP
  int* st   = csr + (size_t)NBUCK * CAP;     // NN
  int* ctv  = st + NN;                       // NN
  int* bcur = ctv + NN;                      // NBUCK*CPAD

  hipMemsetAsync(bcur, 0, NBUCK * CPAD * sizeof(int), stream);
  // blocks: 261 binB + 470 pack + 6252 zm-init + 37512 x-conv = 44495
  binBprep_kernel<<<44495, 256, 0, stream>>>(srcv, dstv, bcur, ebuf,
                                             x, x0, zm, w1, b1, w2, b2, w_ih, b_ih,
                                             w_hh, b_hh, wc1, bc1, wc2, bc2, wp);
  binC_kernel<<<NBUCK, 256, 0, stream>>>(ebuf, bcur, st, ctv, csr);

  int gb = N2 / 64;  // 1563
  aggz_kernel<<<25000, 256, 0, stream>>>(x0, st, ctv, csr, eps, zm);
  mlpgru_kernel<<<gb, 256, 0, stream>>>(zm, x0, w1p, w2p, wihp, whhp, hb0);
  aggz_kernel<<<25000, 256, 0, stream>>>(hb0, st, ctv, csr, eps, zm);
  mlpgru_kernel<<<gb, 256, 0, stream>>>(zm, hb0, w1p, w2p, wihp, whhp, hb1);
  aggz_kernel<<<25000, 256, 0, stream>>>(hb1, st, ctv, csr, eps, zm);
  mlpgru_last_kernel<<<gb, 256, 0, stream>>>(zm, hb1, w1p, w2p, wihp, whhp,
                                             hb0, hb1, wc1p, wc2p, out_x, out_r);
}

// Round 15
// 534.461 us; speedup vs baseline: 1.0537x; 1.0537x over previous
//
#include <hip/hip_runtime.h>

#define NN 100000
#define EE 3200000
#define N2 100032   // NN rounded up to 64
#define NBUCK 782   // ceil(NN/128)
#define CPAD 16     // counter padding (one per 64B line)
#define CHUNK 12288 // edges per binB block
#define CAP 5120    // fixed bucket capacity (mean 4096 + 16 sigma)
#define NB_BINB 261 // ceil(EE/CHUNK)

typedef _Float16 f16;
typedef _Float16 f16x8 __attribute__((ext_vector_type(8)));
typedef float f32x4 __attribute__((ext_vector_type(4)));
typedef unsigned int u32;

#define MFMA(a, b, c) __builtin_amdgcn_mfma_f32_16x16x32_f16((a), (b), (c), 0, 0, 0)

// ---------------- weight pack helper (bias folded at k=95/159) ----------------

__device__ __forceinline__ f16 pack_one(const float* __restrict__ W,
                                        const float* __restrict__ bias, int rel, int K, int Nc,
                                        int KG, int trans, int bslot) {
  int e = rel & 7, nn = (rel >> 3) & 15;
  int g = (rel >> 7) % KG, nb = (rel >> 7) / KG;
  int k = g * 8 + e, n = nb * 16 + nn;
  float v = 0.f;
  if (n < Nc) {
    if (k < K) v = trans ? W[n * K + k] : W[k * Nc + n];
    else if (k == bslot) v = bias[n];
  }
  return (f16)v;
}

// ---------------- fused binB (blocks 0..260) + prep (rest) ----------------

__global__ __launch_bounds__(256) void binBprep_kernel(const int* __restrict__ src,
                                                       const int* __restrict__ dst,
                                                       int* __restrict__ bcur,
                                                       u32* __restrict__ ebuf,
                                                       const float* __restrict__ x,
                                                       f16* __restrict__ xp,
                                                       f16* __restrict__ zm,
                                                       const float* __restrict__ w1,
                                                       const float* __restrict__ b1,
                                                       const float* __restrict__ w2,
                                                       const float* __restrict__ b2,
                                                       const float* __restrict__ wih,
                                                       const float* __restrict__ bih,
                                                       const float* __restrict__ whh,
                                                       const float* __restrict__ bhh,
                                                       const float* __restrict__ wc1,
                                                       const float* __restrict__ bc1,
                                                       const float* __restrict__ wc2,
                                                       const float* __restrict__ bc2,
                                                       f16* __restrict__ wp) {
  __shared__ int hist[NBUCK];
  __shared__ int base[NBUCK];
  int b = blockIdx.x, tid = threadIdx.x;
  if (b < NB_BINB) {
    int e0 = b * CHUNK;
    int e1 = e0 + CHUNK;
    if (e1 > EE) e1 = EE;
    for (int i = tid; i < NBUCK; i += 256) hist[i] = 0;
    __syncthreads();
    for (int e = e0 + tid * 4; e < e1; e += 1024) {
      int4 d = *(const int4*)(dst + e);
      atomicAdd(&hist[d.x >> 7], 1);
      atomicAdd(&hist[d.y >> 7], 1);
      atomicAdd(&hist[d.z >> 7], 1);
      atomicAdd(&hist[d.w >> 7], 1);
    }
    __syncthreads();
    for (int i = tid; i < NBUCK; i += 256) {
      int c = hist[i];
      if (c) base[i] = i * CAP + atomicAdd(&bcur[i * CPAD], c);
    }
    __syncthreads();
    for (int i = tid; i < NBUCK; i += 256) hist[i] = 0;
    __syncthreads();
    for (int e = e0 + tid * 4; e < e1; e += 1024) {
      int4 d = *(const int4*)(dst + e);
      int4 s = *(const int4*)(src + e);
      int bb, loc;
      bb = d.x >> 7; loc = atomicAdd(&hist[bb], 1);
      ebuf[base[bb] + loc] = (u32)s.x | ((u32)(d.x & 127) << 17);
      bb = d.y >> 7; loc = atomicAdd(&hist[bb], 1);
      ebuf[base[bb] + loc] = (u32)s.y | ((u32)(d.y & 127) << 17);
      bb = d.z >> 7; loc = atomicAdd(&hist[bb], 1);
      ebuf[base[bb] + loc] = (u32)s.z | ((u32)(d.z & 127) << 17);
      bb = d.w >> 7; loc = atomicAdd(&hist[bb], 1);
      ebuf[base[bb] + loc] = (u32)s.w | ((u32)(d.w & 127) << 17);
    }
  } else if (b < NB_BINB + 470) {
    int i = (b - NB_BINB) * 256 + tid;   // 120320 = 470*256
    if (i >= 120320) return;
    f16 v;
    if (i < 7680) v = pack_one(w1, b1, i, 75, 75, 12, 0, 95);
    else if (i < 15360) v = pack_one(w2, b2, i - 7680, 75, 75, 12, 0, 95);
    else if (i < 38400) {
      int r = i - 15360, g = r / 7680;
      v = pack_one(wih + g * 5625, bih + g * 75, r - g * 7680, 75, 75, 12, 1, 95);
    } else if (i < 61440) {
      int r = i - 38400, g = r / 7680;
      v = pack_one(whh + g * 5625, bhh + g * 75, r - g * 7680, 75, 75, 12, 1, 95);
    } else if (i < 107520) {
      int rel = i - 61440;
      int e = rel & 7, nn = (rel >> 3) & 15;
      int g = (rel >> 7) % 36, nb = (rel >> 7) / 36;
      int q = g * 8 + e, buf = q / 96, kk = q - buf * 96, n = nb * 16 + nn;
      float f = 0.f;
      if (n < 150) {
        if (kk < 75) f = wc1[(buf * 75 + kk) * 150 + n];
        else if (kk == 95 && buf == 0) f = bc1[n];
      }
      v = (f16)f;
    } else v = pack_one(wc2, bc2, i - 107520, 150, 75, 20, 0, 159);
    wp[i] = v;
  } else if (b < NB_BINB + 470 + 6252) {
    int i = (b - NB_BINB - 470) * 256 + tid;   // N2*16 = 1600512 = 6252*256
    int r = i >> 4, c = i & 15;
    zm[r * 96 + 80 + c] = (f16)(c == 15 ? 1.f : 0.f);
  } else {
    int i = (b - NB_BINB - 470 - 6252) * 256 + tid;  // N2*96 = 9603072 = 37512*256
    int r = i / 96, c = i - r * 96;
    float v = (r < NN && c < 75) ? x[r * 75 + c] : (c == 95 ? 1.f : 0.f);
    xp[i] = (f16)v;
  }
}

// ---------------- binC: per-bucket node-grouping into csr + st/ct ----------------

__global__ __launch_bounds__(256) void binC_kernel(const u32* __restrict__ ebuf,
                                                   const int* __restrict__ bcur,
                                                   int* __restrict__ st,
                                                   int* __restrict__ ct,
                                                   int* __restrict__ csr) {
  __shared__ int cnt[128], sc[128], cur[128];
  int b = blockIdx.x, tid = threadIdx.x;
  int e0 = b * CAP;
  int e1 = e0 + bcur[b * CPAD];   // cursor = bucket count
  if (tid < 128) cnt[tid] = 0;
  __syncthreads();
  for (int e = e0 + tid; e < e1; e += 256) atomicAdd(&cnt[ebuf[e] >> 17], 1);
  __syncthreads();
  if (tid < 128) sc[tid] = cnt[tid];
  __syncthreads();
  for (int off = 1; off < 128; off <<= 1) {
    int t = 0;
    if (tid < 128 && tid >= off) t = sc[tid - off];
    __syncthreads();
    if (tid < 128) sc[tid] += t;
    __syncthreads();
  }
  if (tid < 128) {
    int gpos = e0 + sc[tid] - cnt[tid];
    int node = b * 128 + tid;
    if (node < NN) {
      st[node] = gpos;
      ct[node] = cnt[tid];
    }
    cur[tid] = gpos;
  }
  __syncthreads();
  for (int e = e0 + tid; e < e1; e += 256) {
    u32 p = ebuf[e];
    int pos = atomicAdd(&cur[p >> 17], 1);
    csr[pos] = (int)(p & 0x1FFFFu);
  }
}

// ---------------- aggregation: wave/node, 6-way edge split, 96-stride gather ----------------

__global__ __launch_bounds__(256) void aggz_kernel(const f16* __restrict__ xc,
                                                   const int* __restrict__ st,
                                                   const int* __restrict__ ct,
                                                   const int* __restrict__ csr,
                                                   const float* __restrict__ eps,
                                                   f16* __restrict__ zm) {
  int tid = threadIdx.x;
  int l = tid & 63;
  int n = blockIdx.x * 4 + (tid >> 6);
  if (n >= NN) return;
  int s = l / 10, j = l - s * 10;
  int e0 = st[n], e1 = e0 + ct[n];
  float acc[8] = {0, 0, 0, 0, 0, 0, 0, 0};
  if (l < 60) {
#pragma unroll 4
    for (int e = e0 + s; e < e1; e += 6) {
      int sr = csr[e];
      f16x8 v = *(const f16x8*)(xc + sr * 96 + j * 8);
#pragma unroll
      for (int k = 0; k < 8; ++k) acc[k] += (float)v[k];
    }
  }
  int l1 = (l + 30) & 63, l2 = (l + 10) & 63, l3 = (l + 20) & 63;
#pragma unroll
  for (int k = 0; k < 8; ++k) {
    float t = __shfl(acc[k], l1, 64);
    if (l < 30) acc[k] += t;
    t = __shfl(acc[k], l2, 64);
    if (l < 10) acc[k] += t;
    t = __shfl(acc[k], l3, 64);
    if (l < 10) acc[k] += t;
  }
  if (l < 10) {
    f16x8 self = *(const f16x8*)(xc + n * 96 + j * 8);
    float ep = 1.f + eps[0];
    f16x8 o;
#pragma unroll
    for (int k = 0; k < 8; ++k) o[k] = (f16)(ep * (float)self[k] + acc[k]);
    *(f16x8*)(zm + n * 96 + j * 8) = o;   // cols 0..79; pads pre-set by prep
  }
}

// ---------------- shared device body: MLP + GRU -> h' left in Ld (cols 0..95) ----------------

__device__ __forceinline__ void mlpgru_body(const f16* __restrict__ zm,
                                            const f16* __restrict__ hcur,
                                            const f16* __restrict__ w1p,
                                            const f16* __restrict__ w2p,
                                            const f16* __restrict__ wihp,
                                            const f16* __restrict__ whhp,
                                            f16* Ld, f16* Hd,
                                            int row0, int lm, int lg) {
  const f16* ar = zm + (row0 + lm) * 96;
  const f16* hr = hcur + (row0 + lm) * 96;
  f16x8 a0 = *(const f16x8*)(ar + lg * 8);
  f16x8 a1 = *(const f16x8*)(ar + 32 + lg * 8);
  f16x8 a2 = *(const f16x8*)(ar + 64 + lg * 8);
  f16x8 h0 = *(const f16x8*)(hr + lg * 8);
  f16x8 h1 = *(const f16x8*)(hr + 32 + lg * 8);
  f16x8 h2 = *(const f16x8*)(hr + 64 + lg * 8);
  *(f16x8*)(Hd + lm * 104 + lg * 8) = h0;
  *(f16x8*)(Hd + lm * 104 + 32 + lg * 8) = h1;
  *(f16x8*)(Hd + lm * 104 + 64 + lg * 8) = h2;
  // --- MLP layer 1 (bias folded: zm col95=1, w1p k95=b1)
#pragma unroll
  for (int nb = 0; nb < 5; ++nb) {
    const f16* bp = w1p + ((nb * 12 + lg) * 16 + lm) * 8;
    f32x4 acc = (f32x4){0.f, 0.f, 0.f, 0.f};
    acc = MFMA(a0, *(const f16x8*)bp, acc);
    acc = MFMA(a1, *(const f16x8*)(bp + 512), acc);
    acc = MFMA(a2, *(const f16x8*)(bp + 1024), acc);
#pragma unroll
    for (int r = 0; r < 4; ++r)
      Ld[(lg * 4 + r) * 104 + nb * 16 + lm] = (f16)fmaxf(acc[r], 0.f);
  }
#pragma unroll
  for (int c = 0; c < 4; ++c) {
    int col = 80 + lg * 4 + c;
    Ld[lm * 104 + col] = (f16)(col == 95 ? 1.f : 0.f);
  }
  // --- MLP layer 2
  const f16* Lr = Ld + lm * 104;
  f16x8 c0 = *(const f16x8*)(Lr + lg * 8);
  f16x8 c1 = *(const f16x8*)(Lr + 32 + lg * 8);
  f16x8 c2 = *(const f16x8*)(Lr + 64 + lg * 8);
#pragma unroll
  for (int nb = 0; nb < 5; ++nb) {
    const f16* bp = w2p + ((nb * 12 + lg) * 16 + lm) * 8;
    f32x4 acc = (f32x4){0.f, 0.f, 0.f, 0.f};
    acc = MFMA(c0, *(const f16x8*)bp, acc);
    acc = MFMA(c1, *(const f16x8*)(bp + 512), acc);
    acc = MFMA(c2, *(const f16x8*)(bp + 1024), acc);
#pragma unroll
    for (int r = 0; r < 4; ++r)
      Ld[(lg * 4 + r) * 104 + nb * 16 + lm] = (f16)fmaxf(acc[r], 0.f);
  }
  // --- GRU per-nb (register-lean)
  f16x8 am0 = *(const f16x8*)(Lr + lg * 8);
  f16x8 am1 = *(const f16x8*)(Lr + 32 + lg * 8);
  f16x8 am2 = *(const f16x8*)(Lr + 64 + lg * 8);
#pragma unroll 1
  for (int nb = 0; nb < 5; ++nb) {
    f32x4 rg = (f32x4){0.f, 0.f, 0.f, 0.f};
    f32x4 zg = rg, ni = rg, nh = rg;
#pragma unroll
    for (int s = 0; s < 3; ++s) {
      f16x8 ams = (s == 0) ? am0 : (s == 1) ? am1 : am2;
      f16x8 ahs = (s == 0) ? h0 : (s == 1) ? h1 : h2;
      int fo = ((nb * 12 + s * 4 + lg) * 16 + lm) * 8;
      rg = MFMA(ams, *(const f16x8*)(wihp + fo), rg);
      rg = MFMA(ahs, *(const f16x8*)(whhp + fo), rg);
      zg = MFMA(ams, *(const f16x8*)(wihp + 7680 + fo), zg);
      zg = MFMA(ahs, *(const f16x8*)(whhp + 7680 + fo), zg);
      ni = MFMA(ams, *(const f16x8*)(wihp + 15360 + fo), ni);
      nh = MFMA(ahs, *(const f16x8*)(whhp + 15360 + fo), nh);
    }
#pragma unroll
    for (int r = 0; r < 4; ++r) {
      int n = nb * 16 + lm;
      float hval = (float)Hd[(lg * 4 + r) * 104 + n];
      float rv = 1.f / (1.f + __expf(-rg[r]));
      float zv = 1.f / (1.f + __expf(-zg[r]));
      float u = ni[r] + rv * nh[r];
      float t = __expf(-2.f * fabsf(u));
      float nv = copysignf((1.f - t) / (1.f + t), u);
      float hp = zv * (hval - nv) + nv;
      Ld[(lg * 4 + r) * 104 + n] = (f16)hp;
    }
  }
}

// ---------------- mlpgru (iterations 0,1): h' -> hb_out ----------------

__global__ __launch_bounds__(256) void mlpgru_kernel(const f16* __restrict__ zm,
                                                     const f16* __restrict__ hcur,
                                                     const f16* __restrict__ w1p,
                                                     const f16* __restrict__ w2p,
                                                     const f16* __restrict__ wihp,
                                                     const f16* __restrict__ whhp,
                                                     f16* __restrict__ hb_out) {
  __shared__ f16 Ls[4][16 * 104];
  __shared__ f16 Hs[4][16 * 104];
  int tid = threadIdx.x;
  int w = tid >> 6, l = tid & 63, lm = l & 15, lg = l >> 4;
  int row0 = blockIdx.x * 64 + w * 16;
  f16* Ld = Ls[w];
  mlpgru_body(zm, hcur, w1p, w2p, wihp, whhp, Ld, Hs[w], row0, lm, lg);
#pragma unroll
  for (int k = 0; k < 3; ++k) {
    int p = l + 64 * k;
    int r = p / 12, sl = p - r * 12;
    f16x8 v = *(const f16x8*)(Ld + r * 104 + sl * 8);
    *(f16x8*)(hb_out + (row0 + r) * 96 + sl * 8) = v;
  }
}

// ---------------- mlpgru_last (iteration 2): outx + fused readout, no hb write ----------------

__global__ __launch_bounds__(256) void mlpgru_last_kernel(const f16* __restrict__ zm,
                                                          const f16* __restrict__ hcur,
                                                          const f16* __restrict__ w1p,
                                                          const f16* __restrict__ w2p,
                                                          const f16* __restrict__ wihp,
                                                          const f16* __restrict__ whhp,
                                                          const f16* __restrict__ hb0,
                                                          const f16* __restrict__ hb1,
                                                          const f16* __restrict__ wc1p,
                                                          const f16* __restrict__ wc2p,
                                                          float* __restrict__ outx,
                                                          float* __restrict__ outr) {
  __shared__ f16 LsB[4][3392];     // per-wave: [0,1664)=Ld, [1696,3360)=Hd; reused for r1/fp32
  int tid = threadIdx.x;
  int w = tid >> 6, l = tid & 63, lm = l & 15, lg = l >> 4;
  int row0 = blockIdx.x * 64 + w * 16;
  f16* Ld = LsB[w];
  f16* Hd = LsB[w] + 1696;
  mlpgru_body(zm, hcur, w1p, w2p, wihp, whhp, Ld, Hd, row0, lm, lg);
  // --- outx (fp32 final node states) from Ld
  for (int k = 0; k < 19; ++k) {
    int p = l + 64 * k;
    int gi = row0 * 75 + p;
    if (p < 1200 && gi < NN * 75) {
      int r = p / 75, c = p - r * 75;
      outx[gi] = (float)Ld[r * 104 + c];
    }
  }
  // --- fused readout: cat = [hb0, hb1, h2(Ld)]
  int row = row0 + lm;
  f16x8 a[9];
#pragma unroll
  for (int s = 0; s < 3; ++s) {
    a[s]     = *(const f16x8*)(hb0 + row * 96 + s * 32 + lg * 8);
    a[3 + s] = *(const f16x8*)(hb1 + row * 96 + s * 32 + lg * 8);
    a[6 + s] = *(const f16x8*)(Ld + lm * 104 + s * 32 + lg * 8);
  }
  // r1 = relu(cat @ wc1 + bc1) -> LDS stride 168 (overwrites Ld/Hd; a[] already in regs)
#pragma unroll
  for (int nb = 0; nb < 10; ++nb) {
    f32x4 acc = (f32x4){0.f, 0.f, 0.f, 0.f};
#pragma unroll
    for (int s = 0; s < 9; ++s)
      acc = MFMA(a[s], *(const f16x8*)(wc1p + ((nb * 36 + 4 * s + lg) * 16 + lm) * 8), acc);
#pragma unroll
    for (int r = 0; r < 4; ++r) {
      int n = nb * 16 + lm;
      float v = fmaxf(acc[r], 0.f);
      if (n >= 150) v = (n == 159) ? 1.f : 0.f;   // pad + bias slot (wc2p k159 = bc2)
      LsB[w][(lg * 4 + r) * 168 + n] = (f16)v;
    }
  }
  const f16* Lr2 = LsB[w] + lm * 168;
  f16x8 a2[5];
#pragma unroll
  for (int s = 0; s < 5; ++s) a2[s] = *(const f16x8*)(Lr2 + s * 32 + lg * 8);
  f32x4 acc2[5];
#pragma unroll
  for (int nb = 0; nb < 5; ++nb) {
    acc2[nb] = (f32x4){0.f, 0.f, 0.f, 0.f};
#pragma unroll
    for (int s = 0; s < 5; ++s)
      acc2[nb] = MFMA(a2[s], *(const f16x8*)(wc2p + ((nb * 20 + s * 4 + lg) * 16 + lm) * 8),
                      acc2[nb]);
  }
  float* Lf = (float*)LsB[w];
#pragma unroll
  for (int nb = 0; nb < 5; ++nb)
#pragma unroll
    for (int r = 0; r < 4; ++r) {
      int n = nb * 16 + lm;
      if (n < 75) Lf[(lg * 4 + r) * 76 + n] = acc2[nb][r];
    }
  for (int k = 0; k < 19; ++k) {
    int p = l + 64 * k;
    int gi = row0 * 75 + p;
    if (p < 1200 && gi < NN * 75) {
      int r = p / 75, c = p - r * 75;
      outr[gi] = Lf[r * 76 + c];
    }
  }
}

// ---------------- launch ----------------

extern "C" void kernel_launch(void* const* d_in, const int* in_sizes, int n_in,
                              void* d_out, int out_size, void* d_ws, size_t ws_size,
                              hipStream_t stream) {
  const float* x    = (const float*)d_in[0];
  const int*   ei   = (const int*)d_in[1];
  const float* eps  = (const float*)d_in[2];
  const float* w1   = (const float*)d_in[3];
  const float* b1   = (const float*)d_in[4];
  const float* w2   = (const float*)d_in[5];
  const float* b2   = (const float*)d_in[6];
  const float* w_ih = (const float*)d_in[7];
  const float* w_hh = (const float*)d_in[8];
  const float* b_ih = (const float*)d_in[9];
  const float* b_hh = (const float*)d_in[10];
  const float* wc1  = (const float*)d_in[11];
  const float* bc1  = (const float*)d_in[12];
  const float* wc2  = (const float*)d_in[13];
  const float* bc2  = (const float*)d_in[14];

  const int* srcv = ei;
  const int* dstv = ei + EE;

  float* out_x = (float*)d_out;              // N*75 final node states (fp32)
  float* out_r = out_x + NN * 75;            // N*75 readout (fp32)

  f16* zm   = (f16*)d_ws;                    // N2*96
  f16* x0   = zm + (size_t)N2 * 96;          // N2*96
  f16* hb0  = x0 + (size_t)N2 * 96;          // N2*96
  f16* hb1  = hb0 + (size_t)N2 * 96;         // N2*96
  f16* wp   = hb1 + (size_t)N2 * 96;         // packed weights, 120320 f16
  f16* w1p  = wp;
  f16* w2p  = wp + 7680;
  f16* wihp = wp + 15360;                    // 3 gates x 7680
  f16* whhp = wp + 38400;
  f16* wc1p = wp + 61440;                    // 46080 (KG=36, NB=10)
  f16* wc2p = wp + 107520;                   // 12800
  u32* ebuf = (u32*)(wp + 120320);           // NBUCK*CAP
  int* csr  = (int*)(ebuf + (size_t)NBUCK * CAP);  // NBUCK*CAP
  int* st   = csr + (size_t)NBUCK * CAP;     // NN
  int* ctv  = st + NN;                       // NN
  int* bcur = ctv + NN;                      // NBUCK*CPAD

  hipMemsetAsync(bcur, 0, NBUCK * CPAD * sizeof(int), stream);
  // blocks: 261 binB + 470 pack + 6252 zm-init + 37512 x-conv = 44495
  binBprep_kernel<<<44495, 256, 0, stream>>>(srcv, dstv, bcur, ebuf,
                                             x, x0, zm, w1, b1, w2, b2, w_ih, b_ih,
                                             w_hh, b_hh, wc1, bc1, wc2, bc2, wp);
  binC_kernel<<<NBUCK, 256, 0, stream>>>(ebuf, bcur, st, ctv, csr);

  int gb = N2 / 64;  // 1563
  aggz_kernel<<<25000, 256, 0, stream>>>(x0, st, ctv, csr, eps, zm);
  mlpgru_kernel<<<gb, 256, 0, stream>>>(zm, x0, w1p, w2p, wihp, whhp, hb0);
  aggz_kernel<<<25000, 256, 0, stream>>>(hb0, st, ctv, csr, eps, zm);
  mlpgru_kernel<<<gb, 256, 0, stream>>>(zm, hb0, w1p, w2p, wihp, whhp, hb1);
  aggz_kernel<<<25000, 256, 0, stream>>>(hb1, st, ctv, csr, eps, zm);
  mlpgru_last_kernel<<<gb, 256, 0, stream>>>(zm, hb1, w1p, w2p, wihp, whhp,
                                             hb0, hb1, wc1p, wc2p, out_x, out_r);
}